// Round 2
// baseline (319.070 us; speedup 1.0000x reference)
//
#include <hip/hip_runtime.h>

// YOLO loss: BATCH=16384, CELLS=49, BNUM=2, CLSS=20 -> ELE=30.
// L3-resident streaming reduction. Round-2 structure:
//  - 1-wave (64-thread) blocks, 64 cells/block -> LDS 15.4 KB -> 10 waves/CU
//  - stage raw via float4 global loads + ds_write_b128 (no scalar scatter)
//  - per-cell float2 LDS reads (stride-30, 4-way conflict on reads only)

#define ELE 30
#define TPB 64
#define CPB 64
#define TOTAL_CELLS (16384 * 49)          // 802816
#define NBLOCKS (TOTAL_CELLS / CPB)       // 12544
#define NV (CPB * ELE / 4)                // 480 float4s per input per block

__global__ __launch_bounds__(TPB) void yolo_loss_kernel(
    const float* __restrict__ P, const float* __restrict__ T,
    float* __restrict__ out)
{
    __shared__ float sP[CPB * ELE];   // 7680 B, raw layout
    __shared__ float sT[CPB * ELE];

    const int tid = threadIdx.x;
    const size_t base = (size_t)blockIdx.x * (CPB * ELE);  // *4B = 7680 B -> 16B aligned
    const float4* __restrict__ P4 = reinterpret_cast<const float4*>(P + base);
    const float4* __restrict__ T4 = reinterpret_cast<const float4*>(T + base);

    // ---- stage: register-buffer all loads first (max MLP), then vector LDS writes
    float4 rp[8], rt[8];
    #pragma unroll
    for (int k = 0; k < 7; ++k) {
        rp[k] = P4[tid + 64 * k];
        rt[k] = T4[tid + 64 * k];
    }
    if (tid < 32) {                       // 480 = 7*64 + 32 tail
        rp[7] = P4[tid + 448];
        rt[7] = T4[tid + 448];
    }

    float4* s4P = reinterpret_cast<float4*>(sP);
    float4* s4T = reinterpret_cast<float4*>(sT);
    #pragma unroll
    for (int k = 0; k < 7; ++k) {
        s4P[tid + 64 * k] = rp[k];
        s4T[tid + 64 * k] = rt[k];
    }
    if (tid < 32) {
        s4P[tid + 448] = rp[7];
        s4T[tid + 448] = rt[7];
    }
    __syncthreads();   // single-wave block: compiles to lgkmcnt wait, no barrier drain

    // ---- read own cell (30 floats each, 8B-aligned base -> float2)
    float p[ELE], t[ELE];
    const float2* cp2 = reinterpret_cast<const float2*>(sP + tid * ELE);
    const float2* ct2 = reinterpret_cast<const float2*>(sT + tid * ELE);
    #pragma unroll
    for (int k = 0; k < ELE / 2; ++k) {
        float2 a = cp2[k]; p[2 * k] = a.x; p[2 * k + 1] = a.y;
        float2 b = ct2[k]; t[2 * k] = b.x; t[2 * k + 1] = b.y;
    }

    // ---- per-cell loss (identical math to round 1, absmax was 0.0) ----
    const float conf_flag = t[5];
    const float coord = (conf_flag > 0.0f) ? 1.0f : 0.0f;
    const float noobj = (conf_flag == 0.0f) ? 1.0f : 0.0f;

    const float dc0 = p[4] - t[4];
    const float dc1 = p[9] - t[9];
    const float noobj_conf = noobj * (dc0 * dc0 + dc1 * dc1);

    float px1[2], py1[2], px2[2], py2[2], pa[2];
    float tx1[2], ty1[2], tx2[2], ty2[2], ta[2];
    #pragma unroll
    for (int b = 0; b < 2; ++b) {
        const int o = b * 5;
        float cx = p[o + 0], cy = p[o + 1], w = p[o + 2], h = p[o + 3];
        px1[b] = cx - w * 0.5f; py1[b] = cy - h * 0.5f;
        px2[b] = cx + w * 0.5f; py2[b] = cy + h * 0.5f;
        pa[b]  = (px2[b] - px1[b]) * (py2[b] - py1[b]);
        cx = t[o + 0]; cy = t[o + 1]; w = t[o + 2]; h = t[o + 3];
        tx1[b] = cx - w * 0.5f; ty1[b] = cy - h * 0.5f;
        tx2[b] = cx + w * 0.5f; ty2[b] = cy + h * 0.5f;
        ta[b]  = (tx2[b] - tx1[b]) * (ty2[b] - ty1[b]);
    }

    float iou[2][2];
    #pragma unroll
    for (int pp = 0; pp < 2; ++pp) {
        #pragma unroll
        for (int tt = 0; tt < 2; ++tt) {
            float lx = fmaxf(px1[pp], tx1[tt]);
            float ly = fmaxf(py1[pp], ty1[tt]);
            float rx = fminf(px2[pp], tx2[tt]);
            float ry = fminf(py2[pp], ty2[tt]);
            float iw = fmaxf(rx - lx, 0.0f);
            float ih = fmaxf(ry - ly, 0.0f);
            float inter = iw * ih;
            iou[pp][tt] = inter / (pa[pp] + ta[tt] - inter + 1e-10f);
        }
    }

    // argmax over predictor per target; first-index tiebreak -> strict '>'
    const int b0 = (iou[1][0] > iou[0][0]) ? 1 : 0;
    const int b1 = (iou[1][1] > iou[0][1]) ? 1 : 0;
    const float resp0 = coord * ((b0 == 0 || b1 == 0) ? 1.0f : 0.0f);
    const float resp1 = coord * ((b0 == 1 || b1 == 1) ? 1.0f : 0.0f);

    const float obj_conf = resp0 * dc0 * dc0 + resp1 * dc1 * dc1;

    float d;
    float center = 0.0f, wh = 0.0f;
    d = p[0] - t[0]; center += resp0 * d * d;
    d = p[1] - t[1]; center += resp0 * d * d;
    d = p[5] - t[5]; center += resp1 * d * d;
    d = p[6] - t[6]; center += resp1 * d * d;
    d = p[2] - t[2]; wh += resp0 * d * d;
    d = p[3] - t[3]; wh += resp0 * d * d;
    d = p[7] - t[7]; wh += resp1 * d * d;
    d = p[8] - t[8]; wh += resp1 * d * d;

    float cls = 0.0f;
    #pragma unroll
    for (int k = 10; k < 30; ++k) {
        d = p[k] - t[k];
        cls += d * d;
    }
    cls *= coord;

    float total = 5.0f * (center + wh) + obj_conf + 0.5f * noobj_conf + cls;

    // ---- wave reduction + one atomic per block ----
    #pragma unroll
    for (int off = 32; off > 0; off >>= 1)
        total += __shfl_down(total, off, 64);

    if (tid == 0)
        atomicAdd(out, total);
}

extern "C" void kernel_launch(void* const* d_in, const int* in_sizes, int n_in,
                              void* d_out, int out_size, void* d_ws, size_t ws_size,
                              hipStream_t stream) {
    const float* P = (const float*)d_in[0];
    const float* T = (const float*)d_in[1];
    float* out = (float*)d_out;

    hipMemsetAsync(out, 0, sizeof(float), stream);   // d_out is poisoned 0xAA
    yolo_loss_kernel<<<dim3(NBLOCKS), dim3(TPB), 0, stream>>>(P, T, out);
}

// Round 3
// 274.357 us; speedup vs baseline: 1.1630x; 1.1630x over previous
//
#include <hip/hip_runtime.h>

// YOLO loss: BATCH=16384, CELLS=49, ELE=30. 193 MB HBM-cold streaming reduction.
// Round 3: NO global atomics (round-2 post-mortem: 12544 same-address atomics
// ~= 192 us serialized). Per-block partials -> d_ws, tiny reduce kernel.
// 1-wave blocks, G=4 chunks each, software-pipelined loads (g+1) over compute (g).

#define ELE 30
#define TPB 64
#define CPB 64                              // cells per chunk
#define G   4                               // chunks per block
#define TOTAL_CELLS (16384 * 49)            // 802816
#define NCHUNKS (TOTAL_CELLS / CPB)         // 12544
#define NBLOCKS (NCHUNKS / G)               // 3136
#define V4 (CPB * ELE / 4)                  // 480 float4 per chunk per array

__global__ __launch_bounds__(TPB) void yolo_loss_kernel(
    const float* __restrict__ P, const float* __restrict__ T,
    float* __restrict__ partials)
{
    __shared__ float sP[CPB * ELE];   // 7680 B
    __shared__ float sT[CPB * ELE];

    const int tid = threadIdx.x;
    const float4* __restrict__ P4 = reinterpret_cast<const float4*>(P);
    const float4* __restrict__ T4 = reinterpret_cast<const float4*>(T);
    float4* s4P = reinterpret_cast<float4*>(sP);
    float4* s4T = reinterpret_cast<float4*>(sT);

    float total = 0.0f;

    // preload chunk 0 into registers
    size_t cbase = (size_t)blockIdx.x * G * V4;
    float4 rp[8], rt[8];
    #pragma unroll
    for (int k = 0; k < 7; ++k) {
        rp[k] = P4[cbase + tid + 64 * k];
        rt[k] = T4[cbase + tid + 64 * k];
    }
    if (tid < 32) {                    // 480 = 7*64 + 32 tail
        rp[7] = P4[cbase + tid + 448];
        rt[7] = T4[cbase + tid + 448];
    }

    for (int g = 0; g < G; ++g) {
        // stage chunk g regs -> LDS (vector ds_write_b128)
        #pragma unroll
        for (int k = 0; k < 7; ++k) {
            s4P[tid + 64 * k] = rp[k];
            s4T[tid + 64 * k] = rt[k];
        }
        if (tid < 32) {
            s4P[tid + 448] = rp[7];
            s4T[tid + 448] = rt[7];
        }
        __syncthreads();   // 1-wave block: cheap; drains lgkm, frees rp/rt

        // issue global loads for chunk g+1 (overlap with compute below)
        if (g + 1 < G) {
            const size_t nb = cbase + (size_t)(g + 1) * V4 - (size_t)g * V4 + (size_t)g * V4; // = cbase + (g+1)*V4
            const size_t nbase = (size_t)blockIdx.x * G * V4 + (size_t)(g + 1) * V4;
            #pragma unroll
            for (int k = 0; k < 7; ++k) {
                rp[k] = P4[nbase + tid + 64 * k];
                rt[k] = T4[nbase + tid + 64 * k];
            }
            if (tid < 32) {
                rp[7] = P4[nbase + tid + 448];
                rt[7] = T4[nbase + tid + 448];
            }
            (void)nb;
        }

        // ---- compute own cell from LDS (float2 reads, stride 30) ----
        float p[ELE], t[ELE];
        const float2* cp2 = reinterpret_cast<const float2*>(sP + tid * ELE);
        const float2* ct2 = reinterpret_cast<const float2*>(sT + tid * ELE);
        #pragma unroll
        for (int k = 0; k < ELE / 2; ++k) {
            float2 a = cp2[k]; p[2 * k] = a.x; p[2 * k + 1] = a.y;
            float2 b = ct2[k]; t[2 * k] = b.x; t[2 * k + 1] = b.y;
        }

        const float conf_flag = t[5];
        const float coord = (conf_flag > 0.0f) ? 1.0f : 0.0f;
        const float noobj = (conf_flag == 0.0f) ? 1.0f : 0.0f;

        const float dc0 = p[4] - t[4];
        const float dc1 = p[9] - t[9];
        const float noobj_conf = noobj * (dc0 * dc0 + dc1 * dc1);

        float px1[2], py1[2], px2[2], py2[2], pa[2];
        float tx1[2], ty1[2], tx2[2], ty2[2], ta[2];
        #pragma unroll
        for (int b = 0; b < 2; ++b) {
            const int o = b * 5;
            float cx = p[o + 0], cy = p[o + 1], w = p[o + 2], h = p[o + 3];
            px1[b] = cx - w * 0.5f; py1[b] = cy - h * 0.5f;
            px2[b] = cx + w * 0.5f; py2[b] = cy + h * 0.5f;
            pa[b]  = (px2[b] - px1[b]) * (py2[b] - py1[b]);
            cx = t[o + 0]; cy = t[o + 1]; w = t[o + 2]; h = t[o + 3];
            tx1[b] = cx - w * 0.5f; ty1[b] = cy - h * 0.5f;
            tx2[b] = cx + w * 0.5f; ty2[b] = cy + h * 0.5f;
            ta[b]  = (tx2[b] - tx1[b]) * (ty2[b] - ty1[b]);
        }

        float iou[2][2];
        #pragma unroll
        for (int pp = 0; pp < 2; ++pp) {
            #pragma unroll
            for (int tt = 0; tt < 2; ++tt) {
                float lx = fmaxf(px1[pp], tx1[tt]);
                float ly = fmaxf(py1[pp], ty1[tt]);
                float rx = fminf(px2[pp], tx2[tt]);
                float ry = fminf(py2[pp], ty2[tt]);
                float iw = fmaxf(rx - lx, 0.0f);
                float ih = fmaxf(ry - ly, 0.0f);
                float inter = iw * ih;
                iou[pp][tt] = inter / (pa[pp] + ta[tt] - inter + 1e-10f);
            }
        }

        const int b0 = (iou[1][0] > iou[0][0]) ? 1 : 0;  // first-index tiebreak
        const int b1 = (iou[1][1] > iou[0][1]) ? 1 : 0;
        const float resp0 = coord * ((b0 == 0 || b1 == 0) ? 1.0f : 0.0f);
        const float resp1 = coord * ((b0 == 1 || b1 == 1) ? 1.0f : 0.0f);

        const float obj_conf = resp0 * dc0 * dc0 + resp1 * dc1 * dc1;

        float d;
        float center = 0.0f, wh = 0.0f;
        d = p[0] - t[0]; center += resp0 * d * d;
        d = p[1] - t[1]; center += resp0 * d * d;
        d = p[5] - t[5]; center += resp1 * d * d;
        d = p[6] - t[6]; center += resp1 * d * d;
        d = p[2] - t[2]; wh += resp0 * d * d;
        d = p[3] - t[3]; wh += resp0 * d * d;
        d = p[7] - t[7]; wh += resp1 * d * d;
        d = p[8] - t[8]; wh += resp1 * d * d;

        float cls = 0.0f;
        #pragma unroll
        for (int k = 10; k < 30; ++k) {
            d = p[k] - t[k];
            cls += d * d;
        }
        cls *= coord;

        total += 5.0f * (center + wh) + obj_conf + 0.5f * noobj_conf + cls;

        __syncthreads();   // WAR guard before next iteration's ds_write
    }

    // wave reduction -> one plain store per block (NO atomics)
    #pragma unroll
    for (int off = 32; off > 0; off >>= 1)
        total += __shfl_down(total, off, 64);
    if (tid == 0)
        partials[blockIdx.x] = total;
}

__global__ __launch_bounds__(256) void yolo_reduce_kernel(
    const float* __restrict__ partials, float* __restrict__ out)
{
    __shared__ float sw[4];
    float s = 0.0f;
    for (int i = threadIdx.x; i < NBLOCKS; i += 256)
        s += partials[i];
    #pragma unroll
    for (int off = 32; off > 0; off >>= 1)
        s += __shfl_down(s, off, 64);
    const int wid = threadIdx.x >> 6;
    if ((threadIdx.x & 63) == 0) sw[wid] = s;
    __syncthreads();
    if (threadIdx.x == 0)
        out[0] = sw[0] + sw[1] + sw[2] + sw[3];   // plain overwrite: no memset needed
}

extern "C" void kernel_launch(void* const* d_in, const int* in_sizes, int n_in,
                              void* d_out, int out_size, void* d_ws, size_t ws_size,
                              hipStream_t stream) {
    const float* P = (const float*)d_in[0];
    const float* T = (const float*)d_in[1];
    float* out = (float*)d_out;
    float* partials = (float*)d_ws;    // 3136 floats = 12.5 KB, overwritten fully

    yolo_loss_kernel<<<dim3(NBLOCKS), dim3(TPB), 0, stream>>>(P, T, partials);
    yolo_reduce_kernel<<<dim3(1), dim3(256), 0, stream>>>(partials, out);
}

// Round 4
// 233.949 us; speedup vs baseline: 1.3638x; 1.1727x over previous
//
#include <hip/hip_runtime.h>

// YOLO loss: BATCH=16384, CELLS=49, ELE=30. ~193 MB streaming reduction.
// Round 4: occupancy is the lever (R1: 8 waves/CU = 78us; R3: ~3 waves/CU = 139us).
//  - 256-thread blocks (dispatch well), per-WAVE 32-cell LDS slices (7.7 KB/wave)
//  - __launch_bounds__(256,4): 4 blocks/CU = 16 waves/CU (LDS 30.7 KB/block allows 5)
//  - no __syncthreads in main loop (per-wave slices, in-order DS queue)
//  - G=2 chunks/wave, next-chunk global loads issued before computing current
//  - per-wave partials -> d_ws, tiny reduce kernel (no atomics)

#define ELE 30
#define CPW 32                               // cells per wave-chunk
#define WPB 4                                // waves per block
#define G   2                                // chunks per wave
#define TPB 256
#define TOTAL_CELLS (16384 * 49)             // 802816
#define NBLOCKS (TOTAL_CELLS / (CPW * WPB * G))  // 3136
#define NPART (NBLOCKS * WPB)                // 12544 partials
#define V4C (CPW * ELE / 4)                  // 240 float4 per chunk per array

__device__ __forceinline__ float cell_loss(const float* __restrict__ cp,
                                           const float* __restrict__ ct)
{
    // fields 0..9 of both arrays (box0, box1), float2 reads (8B-aligned: stride 120B)
    float p[10], t[10];
    const float2* cp2 = reinterpret_cast<const float2*>(cp);
    const float2* ct2 = reinterpret_cast<const float2*>(ct);
    #pragma unroll
    for (int k = 0; k < 5; ++k) {
        float2 a = cp2[k]; p[2 * k] = a.x; p[2 * k + 1] = a.y;
        float2 b = ct2[k]; t[2 * k] = b.x; t[2 * k + 1] = b.y;
    }

    const float conf_flag = t[5];
    const float coord = (conf_flag > 0.0f) ? 1.0f : 0.0f;
    const float noobj = (conf_flag == 0.0f) ? 1.0f : 0.0f;

    const float dc0 = p[4] - t[4];
    const float dc1 = p[9] - t[9];
    const float noobj_conf = noobj * (dc0 * dc0 + dc1 * dc1);

    float px1[2], py1[2], px2[2], py2[2], pa[2];
    float tx1[2], ty1[2], tx2[2], ty2[2], ta[2];
    #pragma unroll
    for (int b = 0; b < 2; ++b) {
        const int o = b * 5;
        float cx = p[o + 0], cy = p[o + 1], w = p[o + 2], h = p[o + 3];
        px1[b] = cx - w * 0.5f; py1[b] = cy - h * 0.5f;
        px2[b] = cx + w * 0.5f; py2[b] = cy + h * 0.5f;
        pa[b]  = (px2[b] - px1[b]) * (py2[b] - py1[b]);
        cx = t[o + 0]; cy = t[o + 1]; w = t[o + 2]; h = t[o + 3];
        tx1[b] = cx - w * 0.5f; ty1[b] = cy - h * 0.5f;
        tx2[b] = cx + w * 0.5f; ty2[b] = cy + h * 0.5f;
        ta[b]  = (tx2[b] - tx1[b]) * (ty2[b] - ty1[b]);
    }

    float iou[2][2];
    #pragma unroll
    for (int pp = 0; pp < 2; ++pp) {
        #pragma unroll
        for (int tt = 0; tt < 2; ++tt) {
            float lx = fmaxf(px1[pp], tx1[tt]);
            float ly = fmaxf(py1[pp], ty1[tt]);
            float rx = fminf(px2[pp], tx2[tt]);
            float ry = fminf(py2[pp], ty2[tt]);
            float iw = fmaxf(rx - lx, 0.0f);
            float ih = fmaxf(ry - ly, 0.0f);
            float inter = iw * ih;
            iou[pp][tt] = inter / (pa[pp] + ta[tt] - inter + 1e-10f);
        }
    }

    // argmax over predictor per target; first-index tiebreak -> strict '>'
    const int b0 = (iou[1][0] > iou[0][0]) ? 1 : 0;
    const int b1 = (iou[1][1] > iou[0][1]) ? 1 : 0;
    const float resp0 = coord * ((b0 == 0 || b1 == 0) ? 1.0f : 0.0f);
    const float resp1 = coord * ((b0 == 1 || b1 == 1) ? 1.0f : 0.0f);

    const float obj_conf = resp0 * dc0 * dc0 + resp1 * dc1 * dc1;

    float d;
    float center = 0.0f, wh = 0.0f;
    d = p[0] - t[0]; center += resp0 * d * d;
    d = p[1] - t[1]; center += resp0 * d * d;
    d = p[5] - t[5]; center += resp1 * d * d;
    d = p[6] - t[6]; center += resp1 * d * d;
    d = p[2] - t[2]; wh += resp0 * d * d;
    d = p[3] - t[3]; wh += resp0 * d * d;
    d = p[7] - t[7]; wh += resp1 * d * d;
    d = p[8] - t[8]; wh += resp1 * d * d;

    // class fields 10..29: streamed float2 pairs, small live set
    float cls = 0.0f;
    #pragma unroll
    for (int k = 5; k < 15; ++k) {
        float2 a = cp2[k];
        float2 b = ct2[k];
        float d0 = a.x - b.x;
        float d1 = a.y - b.y;
        cls += d0 * d0 + d1 * d1;
    }
    cls *= coord;

    return 5.0f * (center + wh) + obj_conf + 0.5f * noobj_conf + cls;
}

__global__ __launch_bounds__(TPB, 4) void yolo_loss_kernel(
    const float* __restrict__ P, const float* __restrict__ T,
    float* __restrict__ partials)
{
    // per-wave slice: [960 P floats][960 T floats] = 7680 B; 4 waves = 30720 B
    __shared__ float sm[WPB * 2 * CPW * ELE];

    const int tid  = threadIdx.x;
    const int w    = tid >> 6;
    const int lane = tid & 63;

    float* sw = sm + w * (2 * CPW * ELE);
    float4* s4p = reinterpret_cast<float4*>(sw);             // 240 float4
    float4* s4t = reinterpret_cast<float4*>(sw + CPW * ELE); // 240 float4
    const float4* __restrict__ P4 = reinterpret_cast<const float4*>(P);
    const float4* __restrict__ T4 = reinterpret_cast<const float4*>(T);

    float total = 0.0f;

    // load chunk 0 (coalesced float4; 240 = 3*64 + 48 tail)
    size_t base = (size_t)((blockIdx.x * G + 0) * WPB + w) * V4C;
    float4 rp[4], rt[4];
    rp[0] = P4[base + lane];       rt[0] = T4[base + lane];
    rp[1] = P4[base + 64 + lane];  rt[1] = T4[base + 64 + lane];
    rp[2] = P4[base + 128 + lane]; rt[2] = T4[base + 128 + lane];
    if (lane < 48) {
        rp[3] = P4[base + 192 + lane];
        rt[3] = T4[base + 192 + lane];
    }

    #pragma unroll
    for (int g = 0; g < G; ++g) {
        // stage chunk g into this wave's slice (ds_write_b128; in-order DS queue
        // makes this safe w.r.t. last iteration's reads without any barrier)
        s4p[lane] = rp[0];       s4t[lane] = rt[0];
        s4p[64 + lane] = rp[1];  s4t[64 + lane] = rt[1];
        s4p[128 + lane] = rp[2]; s4t[128 + lane] = rt[2];
        if (lane < 48) {
            s4p[192 + lane] = rp[3];
            s4t[192 + lane] = rt[3];
        }

        // issue next chunk's global loads (overlap with compute below)
        if (g + 1 < G) {
            size_t nb = (size_t)((blockIdx.x * G + (g + 1)) * WPB + w) * V4C;
            rp[0] = P4[nb + lane];       rt[0] = T4[nb + lane];
            rp[1] = P4[nb + 64 + lane];  rt[1] = T4[nb + 64 + lane];
            rp[2] = P4[nb + 128 + lane]; rt[2] = T4[nb + 128 + lane];
            if (lane < 48) {
                rp[3] = P4[nb + 192 + lane];
                rt[3] = T4[nb + 192 + lane];
            }
        }

        // compute: lanes 0..31 each own one cell of this wave's slice
        if (lane < CPW) {
            total += cell_loss(sw + lane * ELE, sw + CPW * ELE + lane * ELE);
        }
    }

    // wave reduction (lanes >=32 contribute 0), one plain store per wave
    #pragma unroll
    for (int off = 32; off > 0; off >>= 1)
        total += __shfl_down(total, off, 64);
    if (lane == 0)
        partials[blockIdx.x * WPB + w] = total;
}

__global__ __launch_bounds__(256) void yolo_reduce_kernel(
    const float* __restrict__ partials, float* __restrict__ out)
{
    __shared__ float swv[4];
    float s = 0.0f;
    for (int i = threadIdx.x; i < NPART; i += 256)
        s += partials[i];
    #pragma unroll
    for (int off = 32; off > 0; off >>= 1)
        s += __shfl_down(s, off, 64);
    const int wid = threadIdx.x >> 6;
    if ((threadIdx.x & 63) == 0) swv[wid] = s;
    __syncthreads();
    if (threadIdx.x == 0)
        out[0] = swv[0] + swv[1] + swv[2] + swv[3];   // plain overwrite, no memset needed
}

extern "C" void kernel_launch(void* const* d_in, const int* in_sizes, int n_in,
                              void* d_out, int out_size, void* d_ws, size_t ws_size,
                              hipStream_t stream) {
    const float* P = (const float*)d_in[0];
    const float* T = (const float*)d_in[1];
    float* out = (float*)d_out;
    float* partials = (float*)d_ws;   // 12544 floats = 49 KB, fully overwritten

    yolo_loss_kernel<<<dim3(NBLOCKS), dim3(TPB), 0, stream>>>(P, T, partials);
    yolo_reduce_kernel<<<dim3(1), dim3(256), 0, stream>>>(partials, out);
}